// Round 2
// baseline (182.823 us; speedup 1.0000x reference)
//
#include <hip/hip_runtime.h>
#include <math.h>

// ---------------------------------------------------------------------------
// FluxAnomalyPredictionTF: F=3, E=6, H=3, d=2, FF=2048, N=16, T=2046, S=W=1024
// 6 dispatches: frontend(+fcc prep) -> attn0 -> ff0 -> attn1 -> ff1 -> final
// ---------------------------------------------------------------------------

#define NB 16
#define TL 2046
#define SL 1024
#define ED 6

__device__ __forceinline__ float relu_(float a){ return fmaxf(a, 0.f); }
__device__ __forceinline__ float fexp2_(float x){ return __builtin_amdgcn_exp2f(x); }

// ------------------------------ frontend -----------------------------------
// grid 256 = 16 n * 16 stiles ; 192 threads = 3 waves (wave = feature f)
// Also builds fcc weight layout for the FF kernels (needed 2 dispatches later).
// fcc[l][j][16]: [0..5]=f1w row j, [6]=f1b[j], [8..13]=f2w[:,j], rest 0
__global__ __launch_bounds__(192) void frontend_kernel(
  const float* __restrict__ x, const float* __restrict__ k64,
  const float* __restrict__ b64, const float* __restrict__ k16, const float* __restrict__ b16,
  const float* __restrict__ k8,  const float* __restrict__ b8,
  const float* __restrict__ kw3, const float* __restrict__ bw3,
  const float* __restrict__ km3, const float* __restrict__ bm3,
  const float* __restrict__ kn3, const float* __restrict__ bn3,
  const float* __restrict__ fc1w, const float* __restrict__ fc1b,
  const float* __restrict__ fc2w, const float* __restrict__ fc2b,
  const float* __restrict__ f1w, const float* __restrict__ f1b,
  const float* __restrict__ f2w,
  float* __restrict__ fcc, float* __restrict__ seq)
{
  __shared__ float xt[3][200];
  __shared__ float k64s[3*64*8];
  __shared__ float flat_s[64][44];
  __shared__ float h1_s[64][20];
  const int tid  = threadIdx.x;
  const int f    = tid >> 6;
  const int lane = tid & 63;
  const int n    = blockIdx.x >> 4;
  const int s0   = (blockIdx.x & 15) << 6;
  const int s    = s0 + lane;

  // ---- build fcc (global, for ff kernels) ----
  for (int i = blockIdx.x*192 + tid; i < 2*2048*16; i += 256*192){
    int l = i >> 15, r = i & 32767, j = r >> 4, c = r & 15;
    float v = 0.f;
    if (c < 6)       v = f1w[(l*2048 + j)*6 + c];
    else if (c == 6) v = f1b[l*2048 + j];
    else if (c >= 8 && c < 14) v = f2w[(l*6 + (c-8))*2048 + j];
    fcc[i] = v;
  }

  for (int i = tid; i < 600; i += 192){
    int ff = i / 200, pos = i - ff*200;
    int xp = 2*s0 - 39 + pos;
    xt[ff][pos] = (xp >= 0 && xp < TL) ? x[(n*TL + xp)*3 + ff] : 0.f;
  }
  // k64 transpose into LDS: k64s[f*512 + t*8 + k] = k64[k][f][t]
  for (int i = tid; i < 1536; i += 192){
    int ff = i >> 9, r = i & 511, t = r >> 3, k = r & 7;
    k64s[i] = k64[k*192 + ff*64 + t];
  }
  __syncthreads();

  // register x window: xr[i] = x[n][2s-39+i]
  float xr[74];
  {
    const int b = 2*lane;
    #pragma unroll
    for (int i = 0; i < 74; i++) xr[i] = xt[f][b + i];
  }

  // ---- wide: 64-tap, 8 kernels at w=s, plus edge (w=s-1,k=7),(w=s+1,k=0) ----
  float accw[8], acc_e0, acc_e1;
  #pragma unroll
  for (int k = 0; k < 8; k++) accw[k] = b64[k*3 + f];
  acc_e0 = accw[7]; acc_e1 = accw[0];
  {
    const float* kp = &k64s[f*512];
    #pragma unroll
    for (int t = 0; t < 64; t++){
      float4 wa = *(const float4*)(kp + t*8);
      float4 wb = *(const float4*)(kp + t*8 + 4);
      float xm = xr[8 + t];
      accw[0] = fmaf(xm, wa.x, accw[0]);
      accw[1] = fmaf(xm, wa.y, accw[1]);
      accw[2] = fmaf(xm, wa.z, accw[2]);
      accw[3] = fmaf(xm, wa.w, accw[3]);
      accw[4] = fmaf(xm, wb.x, accw[4]);
      accw[5] = fmaf(xm, wb.y, accw[5]);
      accw[6] = fmaf(xm, wb.z, accw[6]);
      accw[7] = fmaf(xm, wb.w, accw[7]);
      acc_e0 = fmaf(xr[6 + t],  wb.w, acc_e0);
      acc_e1 = fmaf(xr[10 + t], wa.x, acc_e1);
    }
  }
  float yw[10];
  yw[0] = (s > 0) ? 5.f*relu_(acc_e0) : 0.f;
  #pragma unroll
  for (int c = 1; c <= 8; c++) yw[c] = 5.f*relu_(accw[c-1]);
  yw[9] = (s < 1023) ? 5.f*relu_(acc_e1) : 0.f;

  // ---- mid: 16-tap ----
  float w16r[16];
  #pragma unroll
  for (int t = 0; t < 16; t++) w16r[t] = k16[f*16 + t];
  const float bb16 = b16[f];
  float ym[10];
  #pragma unroll
  for (int ci = 0; ci < 10; ci++){
    const int b = (ci == 0) ? 54 : ((ci == 9) ? 2 : 8*(ci-1));
    float a = bb16;
    #pragma unroll
    for (int t = 0; t < 16; t++) a = fmaf(xr[b + t], w16r[t], a);
    ym[ci] = relu_(a);
  }
  if (s == 0)    ym[0] = 0.f;
  if (s == 1023) ym[9] = 0.f;

  // ---- nar: 8-tap, max over 4 sub-windows ----
  float w8r[8];
  #pragma unroll
  for (int t = 0; t < 8; t++) w8r[t] = k8[f*8 + t];
  const float bb8 = b8[f];
  float yn[10];
  #pragma unroll
  for (int ci = 0; ci < 10; ci++){
    float m = -3.0e38f;
    #pragma unroll
    for (int j2 = 0; j2 < 4; j2++){
      const int b = (ci == 0) ? (58 + 2*j2)
                  : ((ci == 9) ? (6 + 2*j2)
                               : (4 + 2*(4*(ci-1) + j2)));
      float a = bb8;
      #pragma unroll
      for (int t = 0; t < 8; t++) a = fmaf(xr[b + t], w8r[t], a);
      m = fmaxf(m, a);
    }
    yn[ci] = relu_(m);
  }
  if (s == 0)    yn[0] = 0.f;
  if (s == 1023) yn[9] = 0.f;

  // ---- conv3 + relu + pool2 -> flat ----
  {
    float c0 = kw3[f*3], c1 = kw3[f*3+1], c2 = kw3[f*3+2], bb = bw3[f];
    #pragma unroll
    for (int q = 0; q < 4; q++){
      float z0 = relu_(fmaf(c0, yw[2*q],   fmaf(c1, yw[2*q+1], fmaf(c2, yw[2*q+2], bb))));
      float z1 = relu_(fmaf(c0, yw[2*q+1], fmaf(c1, yw[2*q+2], fmaf(c2, yw[2*q+3], bb))));
      flat_s[lane][q*3 + f] = fmaxf(z0, z1);
    }
  }
  {
    float c0 = km3[f*3], c1 = km3[f*3+1], c2 = km3[f*3+2], bb = bm3[f];
    #pragma unroll
    for (int q = 0; q < 4; q++){
      float z0 = relu_(fmaf(c0, ym[2*q],   fmaf(c1, ym[2*q+1], fmaf(c2, ym[2*q+2], bb))));
      float z1 = relu_(fmaf(c0, ym[2*q+1], fmaf(c1, ym[2*q+2], fmaf(c2, ym[2*q+3], bb))));
      flat_s[lane][12 + q*3 + f] = fmaxf(z0, z1);
    }
  }
  {
    float c0 = kn3[f*3], c1 = kn3[f*3+1], c2 = kn3[f*3+2], bb = bn3[f];
    #pragma unroll
    for (int q = 0; q < 4; q++){
      float z0 = relu_(fmaf(c0, yn[2*q],   fmaf(c1, yn[2*q+1], fmaf(c2, yn[2*q+2], bb))));
      float z1 = relu_(fmaf(c0, yn[2*q+1], fmaf(c1, yn[2*q+2], fmaf(c2, yn[2*q+3], bb))));
      flat_s[lane][24 + q*3 + f] = fmaxf(z0, z1);
    }
  }
  __syncthreads();

  // ---- fc1: wave f computes outputs [6f, 6f+6) ----
  #pragma unroll
  for (int oi = 0; oi < 6; oi++){
    const int o = 6*f + oi;
    float acc = fc1b[o];
    const float4* wrow = (const float4*)(fc1w + o*36);
    const float4* frow = (const float4*)(&flat_s[lane][0]);
    #pragma unroll
    for (int i = 0; i < 9; i++){
      float4 wv = wrow[i], fv = frow[i];
      acc = fmaf(wv.x, fv.x, acc); acc = fmaf(wv.y, fv.y, acc);
      acc = fmaf(wv.z, fv.z, acc); acc = fmaf(wv.w, fv.w, acc);
    }
    h1_s[lane][o] = relu_(acc);
  }
  __syncthreads();

  // ---- fc2: wave f computes e = 2f, 2f+1 ----
  #pragma unroll
  for (int ei = 0; ei < 2; ei++){
    const int e = 2*f + ei;
    float acc = fc2b[e];
    #pragma unroll
    for (int o = 0; o < 18; o++) acc = fmaf(h1_s[lane][o], fc2w[e*18 + o], acc);
    seq[(n*SL + s)*ED + e] = relu_(acc);
  }
}

// ------------------------------ attention ----------------------------------
// grid 768 = 16 n * 3 h * 16 stiles ; 128 threads: 64 rows x 2 t-halves.
// qkv fused (recompute per block); scale*log2(e) folded into K; exp2 softmax.
__global__ __launch_bounds__(128) void attn_kernel(
  const float* __restrict__ seq, const float* __restrict__ inw,
  const float* __restrict__ inb, float* __restrict__ att_out, int layer)
{
  __shared__ float4 kv[1024];
  const int tid = threadIdx.x;
  const int bid = blockIdx.x;
  const int n = bid / 48;
  const int r = bid % 48;
  const int h = r >> 4;
  const int stile = r & 15;
  const float* W = inw + layer*108;
  const float* B = inb + layer*18;
  const int h2 = 2*h;
  const float* seqn = seq + n*SL*ED;
  const float SC = 1.0201265650432017f; // (1/sqrt(2)) * log2(e)

  float wk0[6], wk1[6], wv0[6], wv1[6];
  #pragma unroll
  for (int e = 0; e < 6; e++){
    wk0[e] = W[(6 + h2)*6 + e];  wk1[e] = W[(7 + h2)*6 + e];
    wv0[e] = W[(12 + h2)*6 + e]; wv1[e] = W[(13 + h2)*6 + e];
  }
  const float bk0 = B[6 + h2], bk1 = B[7 + h2], bv0 = B[12 + h2], bv1 = B[13 + h2];

  for (int t = tid; t < 1024; t += 128){
    const float* sr = seqn + t*6;
    float a0 = sr[0], a1 = sr[1], a2 = sr[2], a3 = sr[3], a4 = sr[4], a5 = sr[5];
    float k0 = bk0 + a0*wk0[0] + a1*wk0[1] + a2*wk0[2] + a3*wk0[3] + a4*wk0[4] + a5*wk0[5];
    float k1 = bk1 + a0*wk1[0] + a1*wk1[1] + a2*wk1[2] + a3*wk1[3] + a4*wk1[4] + a5*wk1[5];
    float v0 = bv0 + a0*wv0[0] + a1*wv0[1] + a2*wv0[2] + a3*wv0[3] + a4*wv0[4] + a5*wv0[5];
    float v1 = bv1 + a0*wv1[0] + a1*wv1[1] + a2*wv1[2] + a3*wv1[3] + a4*wv1[4] + a5*wv1[5];
    kv[t] = make_float4(k0*SC, k1*SC, v0, v1);
  }

  const int srow = stile*64 + (tid >> 1);
  const int half = tid & 1;
  float q0, q1;
  {
    const float* sr = seqn + srow*6;
    float a0 = sr[0], a1 = sr[1], a2 = sr[2], a3 = sr[3], a4 = sr[4], a5 = sr[5];
    q0 = B[h2]   + a0*W[h2*6]     + a1*W[h2*6+1]     + a2*W[h2*6+2]     + a3*W[h2*6+3]     + a4*W[h2*6+4]     + a5*W[h2*6+5];
    q1 = B[h2+1] + a0*W[(h2+1)*6] + a1*W[(h2+1)*6+1] + a2*W[(h2+1)*6+2] + a3*W[(h2+1)*6+3] + a4*W[(h2+1)*6+4] + a5*W[(h2+1)*6+5];
  }
  __syncthreads();

  float l = 0.f, o0 = 0.f, o1 = 0.f;
  const int t0 = half * 512;
  #pragma unroll 8
  for (int t = t0; t < t0 + 512; t++){
    float4 K = kv[t];
    float sc = fmaf(q0, K.x, q1*K.y);
    float p  = fexp2_(sc);
    l += p;
    o0 = fmaf(p, K.z, o0);
    o1 = fmaf(p, K.w, o1);
  }
  l  += __shfl_xor(l, 1);
  o0 += __shfl_xor(o0, 1);
  o1 += __shfl_xor(o1, 1);
  if (half == 0){
    float inv = 1.0f / l;
    float* orow = att_out + (n*SL + srow)*ED + h2;
    orow[0] = o0*inv; orow[1] = o1*inv;
  }
}

// ------------------- fused oproj+LN1 + FF + LN2 -----------------------------
// grid 256 blocks (64 tokens each), 1024 threads = 16 waves.
// wave w covers j in [w*128,(w+1)*128); lane=(tp 0..15, ss 0..3):
//   ss handles j = w*128 + ss*32 + i; tp handles tokens tp*4..tp*4+3.
// Weights read straight from L2-hot fcc (coalesced 64B rows) — no LDS staging.
// In-wave shuffle reduce over ss, LDS tree over 16 waves, LN2 in epilogue.
__global__ __launch_bounds__(1024) void ff_kernel(
  const float* __restrict__ seq_in, const float* __restrict__ att,
  const float* __restrict__ fcc,
  const float* __restrict__ ow, const float* __restrict__ ob,
  const float* __restrict__ l1w, const float* __restrict__ l1b,
  const float* __restrict__ f2b, const float* __restrict__ l2w,
  const float* __restrict__ l2b,
  float* __restrict__ seq_out, int layer)
{
  __shared__ float sM[64][6];        // seq_mid = LN1(seq + oproj(att))
  __shared__ float red[16][16][24];  // [wave][tp][t*6+e]
  __shared__ float fin[64][6];
  const int tid  = threadIdx.x;
  const int tok0 = blockIdx.x * 64;

  // ---- oproj + residual + LN1 for this block's 64 tokens ----
  if (tid < 64){
    const int token = tok0 + tid;
    const float* a  = att + token*6;
    const float* W  = ow + layer*36;
    float av[6];
    #pragma unroll
    for (int e = 0; e < 6; e++) av[e] = a[e];
    float y[6]; float mu = 0.f;
    #pragma unroll
    for (int e = 0; e < 6; e++){
      float o = ob[layer*6 + e];
      #pragma unroll
      for (int e2 = 0; e2 < 6; e2++) o = fmaf(av[e2], W[e*6 + e2], o);
      y[e] = seq_in[token*6 + e] + o;
      mu += y[e];
    }
    mu *= (1.f/6.f);
    float var = 0.f;
    #pragma unroll
    for (int e = 0; e < 6; e++){ float d = y[e] - mu; var = fmaf(d, d, var); }
    var *= (1.f/6.f);
    float rstd = rsqrtf(var + 1e-5f);
    #pragma unroll
    for (int e = 0; e < 6; e++)
      sM[tid][e] = (y[e] - mu)*rstd*l1w[layer*6 + e] + l1b[layer*6 + e];
  }
  __syncthreads();

  const int w = tid >> 6, lane = tid & 63, tp = lane >> 2, ss = lane & 3;

  // token values in registers (broadcast LDS reads within tp-group)
  float sv[4][6];
  {
    const float* sp = &sM[tp*4][0];
    #pragma unroll
    for (int t = 0; t < 4; t++)
      #pragma unroll
      for (int e = 0; e < 6; e++) sv[t][e] = sp[t*6 + e];
  }
  float acc[4][6];
  #pragma unroll
  for (int t = 0; t < 4; t++)
    #pragma unroll
    for (int e = 0; e < 6; e++) acc[t][e] = 0.f;

  const float4* base = (const float4*)(fcc + (size_t)(layer*2048 + w*128 + ss*32)*16);
  #pragma unroll 2
  for (int i = 0; i < 32; i++){
    float4 w0 = base[i*4+0], w1 = base[i*4+1], w2 = base[i*4+2], w3 = base[i*4+3];
    #pragma unroll
    for (int t = 0; t < 4; t++){
      float h = w1.z;
      h = fmaf(sv[t][0], w0.x, h); h = fmaf(sv[t][1], w0.y, h);
      h = fmaf(sv[t][2], w0.z, h); h = fmaf(sv[t][3], w0.w, h);
      h = fmaf(sv[t][4], w1.x, h); h = fmaf(sv[t][5], w1.y, h);
      h = relu_(h);
      acc[t][0] = fmaf(h, w2.x, acc[t][0]); acc[t][1] = fmaf(h, w2.y, acc[t][1]);
      acc[t][2] = fmaf(h, w2.z, acc[t][2]); acc[t][3] = fmaf(h, w2.w, acc[t][3]);
      acc[t][4] = fmaf(h, w3.x, acc[t][4]); acc[t][5] = fmaf(h, w3.y, acc[t][5]);
    }
  }

  // reduce across ss (lanes 0..3 of each tp-group)
  #pragma unroll
  for (int t = 0; t < 4; t++)
    #pragma unroll
    for (int e = 0; e < 6; e++){
      acc[t][e] += __shfl_xor(acc[t][e], 1);
      acc[t][e] += __shfl_xor(acc[t][e], 2);
    }
  if (ss == 0){
    #pragma unroll
    for (int t = 0; t < 4; t++)
      #pragma unroll
      for (int e = 0; e < 6; e++) red[w][tp][t*6 + e] = acc[t][e];
  }
  __syncthreads();

  // reduce across 16 waves: 384 values (64 tok x 6 e)
  if (tid < 384){
    const int tl = tid / 6, e = tid - tl*6;
    const int rtp = tl >> 2, rt = tl & 3;
    float sum = 0.f;
    #pragma unroll
    for (int wi = 0; wi < 16; wi++) sum += red[wi][rtp][rt*6 + e];
    fin[tl][e] = sum;
  }
  __syncthreads();

  // residual + f2 bias + LN2 -> seq_out
  if (tid < 64){
    const int token = tok0 + tid;
    float y[6]; float mu = 0.f;
    #pragma unroll
    for (int e = 0; e < 6; e++){
      y[e] = sM[tid][e] + fin[tid][e] + f2b[layer*6 + e];
      mu += y[e];
    }
    mu *= (1.f/6.f);
    float var = 0.f;
    #pragma unroll
    for (int e = 0; e < 6; e++){ float d = y[e] - mu; var = fmaf(d, d, var); }
    var *= (1.f/6.f);
    float rstd = rsqrtf(var + 1e-5f);
    #pragma unroll
    for (int e = 0; e < 6; e++)
      seq_out[token*6 + e] = (y[e] - mu)*rstd*l2w[layer*6 + e] + l2b[layer*6 + e];
  }
}

// ------------------------------- head ----------------------------------------
__global__ __launch_bounds__(192) void final_kernel(
  const float* __restrict__ seq, const float* __restrict__ o1w,
  const float* __restrict__ o1b, const float* __restrict__ o2w,
  float* __restrict__ out)
{
  __shared__ float red[6][33];
  __shared__ float pooled[6];
  const int n = blockIdx.x, tid = threadIdx.x, e = tid >> 5, ch = tid & 31;
  float s = 0.f;
  for (int i = ch; i < 1024; i += 32) s += seq[(n*SL + i)*ED + e];
  red[e][ch] = s;
  __syncthreads();
  if (tid < 6){
    float t = 0.f;
    for (int i = 0; i < 32; i++) t += red[tid][i];
    pooled[tid] = fmaxf(t * (1.f/1024.f), 0.f);
  }
  __syncthreads();
  if (tid == 0){
    float o1[7];
    #pragma unroll
    for (int o = 0; o < 7; o++){
      float a = o1b[o];
      #pragma unroll
      for (int e2 = 0; e2 < 6; e2++) a = fmaf(pooled[e2], o1w[o*6 + e2], a);
      o1[o] = relu_(a);
    }
    float lg[4];
    #pragma unroll
    for (int c = 0; c < 4; c++){
      float a = 0.f;
      #pragma unroll
      for (int o = 0; o < 7; o++) a = fmaf(o1[o], o2w[c*7 + o], a);
      lg[c] = a;
    }
    float m = fmaxf(fmaxf(lg[0], lg[1]), fmaxf(lg[2], lg[3]));
    float sum = 0.f;
    #pragma unroll
    for (int c = 0; c < 4; c++) sum += expf(lg[c] - m);
    float lse = m + logf(sum);
    #pragma unroll
    for (int c = 0; c < 4; c++) out[n*4 + c] = lg[c] - lse;
  }
}

// ------------------------------- launch --------------------------------------
extern "C" void kernel_launch(void* const* d_in, const int* in_sizes, int n_in,
                              void* d_out, int out_size, void* d_ws, size_t ws_size,
                              hipStream_t stream)
{
  const float* x    = (const float*)d_in[0];
  const float* k64  = (const float*)d_in[1];
  const float* b64  = (const float*)d_in[2];
  const float* k16  = (const float*)d_in[3];
  const float* b16  = (const float*)d_in[4];
  const float* k8   = (const float*)d_in[5];
  const float* b8   = (const float*)d_in[6];
  const float* kw3  = (const float*)d_in[7];
  const float* bw3  = (const float*)d_in[8];
  const float* km3  = (const float*)d_in[9];
  const float* bm3  = (const float*)d_in[10];
  const float* kn3  = (const float*)d_in[11];
  const float* bn3  = (const float*)d_in[12];
  const float* fc1w = (const float*)d_in[13];
  const float* fc1b = (const float*)d_in[14];
  const float* fc2w = (const float*)d_in[15];
  const float* fc2b = (const float*)d_in[16];
  const float* inw  = (const float*)d_in[17];
  const float* inb  = (const float*)d_in[18];
  const float* ow   = (const float*)d_in[19];
  const float* ob   = (const float*)d_in[20];
  const float* l1w  = (const float*)d_in[21];
  const float* l1b  = (const float*)d_in[22];
  const float* l2w  = (const float*)d_in[23];
  const float* l2b  = (const float*)d_in[24];
  const float* f1w  = (const float*)d_in[25];
  const float* f1b  = (const float*)d_in[26];
  const float* f2w  = (const float*)d_in[27];
  const float* f2b  = (const float*)d_in[28];
  const float* o1w  = (const float*)d_in[29];
  const float* o1b  = (const float*)d_in[30];
  const float* o2w  = (const float*)d_in[31];
  float* out = (float*)d_out;

  float* w = (float*)d_ws;
  float* seq_a = w;                  // 98304
  float* seq_b = w + 98304;          // 98304
  float* att   = w + 196608;         // 98304
  float* fcc   = w + 294912;         // 65536
  // total 360448 floats ~= 1.4 MB

  frontend_kernel<<<256, 192, 0, stream>>>(x, k64, b64, k16, b16, k8, b8,
      kw3, bw3, km3, bm3, kn3, bn3, fc1w, fc1b, fc2w, fc2b,
      f1w, f1b, f2w, fcc, seq_a);
  attn_kernel<<<768, 128, 0, stream>>>(seq_a, inw, inb, att, 0);
  ff_kernel<<<256, 1024, 0, stream>>>(seq_a, att, fcc, ow, ob, l1w, l1b,
      f2b, l2w, l2b, seq_b, 0);
  attn_kernel<<<768, 128, 0, stream>>>(seq_b, inw, inb, att, 1);
  ff_kernel<<<256, 1024, 0, stream>>>(seq_b, att, fcc, ow, ob, l1w, l1b,
      f2b, l2w, l2b, seq_a, 1);
  final_kernel<<<16, 192, 0, stream>>>(seq_a, o1w, o1b, o2w, out);
}

// Round 3
// 88.822 us; speedup vs baseline: 2.0583x; 2.0583x over previous
//
#include <hip/hip_runtime.h>
#include <math.h>

// ---------------------------------------------------------------------------
// FluxAnomalyPredictionTF: F=3, E=6, H=3, d=2, FF=2048, N=16, T=2046, S=W=1024
// 8 dispatches: frontend(+fcc) -> [attn -> ff -> ffln]x2 -> final
// ---------------------------------------------------------------------------

#define NB 16
#define TL 2046
#define SL 1024
#define ED 6

__device__ __forceinline__ float relu_(float a){ return fmaxf(a, 0.f); }
__device__ __forceinline__ float fexp2_(float x){ return __builtin_amdgcn_exp2f(x); }

// ------------------------------ frontend -----------------------------------
// grid 256 = 16 n * 16 stiles ; 192 threads = 3 waves (wave = feature f)
// Also builds fcc weight layout for the FF kernels.
// fcc[l][j][16]: [0..5]=f1w row j, [6]=f1b[j], [8..13]=f2w[:,j], rest 0
__global__ __launch_bounds__(192) void frontend_kernel(
  const float* __restrict__ x, const float* __restrict__ k64,
  const float* __restrict__ b64, const float* __restrict__ k16, const float* __restrict__ b16,
  const float* __restrict__ k8,  const float* __restrict__ b8,
  const float* __restrict__ kw3, const float* __restrict__ bw3,
  const float* __restrict__ km3, const float* __restrict__ bm3,
  const float* __restrict__ kn3, const float* __restrict__ bn3,
  const float* __restrict__ fc1w, const float* __restrict__ fc1b,
  const float* __restrict__ fc2w, const float* __restrict__ fc2b,
  const float* __restrict__ f1w, const float* __restrict__ f1b,
  const float* __restrict__ f2w,
  float* __restrict__ fcc, float* __restrict__ seq)
{
  __shared__ float xt[3][200];
  __shared__ float k64s[3*64*8];
  __shared__ float flat_s[64][44];
  __shared__ float h1_s[64][20];
  const int tid  = threadIdx.x;
  const int f    = tid >> 6;
  const int lane = tid & 63;
  const int n    = blockIdx.x >> 4;
  const int s0   = (blockIdx.x & 15) << 6;
  const int s    = s0 + lane;

  // ---- build fcc (global, for ff kernels) ----
  for (int i = blockIdx.x*192 + tid; i < 2*2048*16; i += 256*192){
    int l = i >> 15, r = i & 32767, j = r >> 4, c = r & 15;
    float v = 0.f;
    if (c < 6)       v = f1w[(l*2048 + j)*6 + c];
    else if (c == 6) v = f1b[l*2048 + j];
    else if (c >= 8 && c < 14) v = f2w[(l*6 + (c-8))*2048 + j];
    fcc[i] = v;
  }

  for (int i = tid; i < 600; i += 192){
    int ff = i / 200, pos = i - ff*200;
    int xp = 2*s0 - 39 + pos;
    xt[ff][pos] = (xp >= 0 && xp < TL) ? x[(n*TL + xp)*3 + ff] : 0.f;
  }
  // k64 transpose into LDS: k64s[f*512 + t*8 + k] = k64[k][f][t]
  for (int i = tid; i < 1536; i += 192){
    int ff = i >> 9, r = i & 511, t = r >> 3, k = r & 7;
    k64s[i] = k64[k*192 + ff*64 + t];
  }
  __syncthreads();

  float xr[74];
  {
    const int b = 2*lane;
    #pragma unroll
    for (int i = 0; i < 74; i++) xr[i] = xt[f][b + i];
  }

  // ---- wide: 64-tap ----
  float accw[8], acc_e0, acc_e1;
  #pragma unroll
  for (int k = 0; k < 8; k++) accw[k] = b64[k*3 + f];
  acc_e0 = accw[7]; acc_e1 = accw[0];
  {
    const float* kp = &k64s[f*512];
    #pragma unroll
    for (int t = 0; t < 64; t++){
      float4 wa = *(const float4*)(kp + t*8);
      float4 wb = *(const float4*)(kp + t*8 + 4);
      float xm = xr[8 + t];
      accw[0] = fmaf(xm, wa.x, accw[0]);
      accw[1] = fmaf(xm, wa.y, accw[1]);
      accw[2] = fmaf(xm, wa.z, accw[2]);
      accw[3] = fmaf(xm, wa.w, accw[3]);
      accw[4] = fmaf(xm, wb.x, accw[4]);
      accw[5] = fmaf(xm, wb.y, accw[5]);
      accw[6] = fmaf(xm, wb.z, accw[6]);
      accw[7] = fmaf(xm, wb.w, accw[7]);
      acc_e0 = fmaf(xr[6 + t],  wb.w, acc_e0);
      acc_e1 = fmaf(xr[10 + t], wa.x, acc_e1);
    }
  }
  float yw[10];
  yw[0] = (s > 0) ? 5.f*relu_(acc_e0) : 0.f;
  #pragma unroll
  for (int c = 1; c <= 8; c++) yw[c] = 5.f*relu_(accw[c-1]);
  yw[9] = (s < 1023) ? 5.f*relu_(acc_e1) : 0.f;

  // ---- mid: 16-tap ----
  float w16r[16];
  #pragma unroll
  for (int t = 0; t < 16; t++) w16r[t] = k16[f*16 + t];
  const float bb16 = b16[f];
  float ym[10];
  #pragma unroll
  for (int ci = 0; ci < 10; ci++){
    const int b = (ci == 0) ? 54 : ((ci == 9) ? 2 : 8*(ci-1));
    float a = bb16;
    #pragma unroll
    for (int t = 0; t < 16; t++) a = fmaf(xr[b + t], w16r[t], a);
    ym[ci] = relu_(a);
  }
  if (s == 0)    ym[0] = 0.f;
  if (s == 1023) ym[9] = 0.f;

  // ---- nar: 8-tap, max over 4 ----
  float w8r[8];
  #pragma unroll
  for (int t = 0; t < 8; t++) w8r[t] = k8[f*8 + t];
  const float bb8 = b8[f];
  float yn[10];
  #pragma unroll
  for (int ci = 0; ci < 10; ci++){
    float m = -3.0e38f;
    #pragma unroll
    for (int j2 = 0; j2 < 4; j2++){
      const int b = (ci == 0) ? (58 + 2*j2)
                  : ((ci == 9) ? (6 + 2*j2)
                               : (4 + 2*(4*(ci-1) + j2)));
      float a = bb8;
      #pragma unroll
      for (int t = 0; t < 8; t++) a = fmaf(xr[b + t], w8r[t], a);
      m = fmaxf(m, a);
    }
    yn[ci] = relu_(m);
  }
  if (s == 0)    yn[0] = 0.f;
  if (s == 1023) yn[9] = 0.f;

  // ---- conv3 + relu + pool2 -> flat ----
  {
    float c0 = kw3[f*3], c1 = kw3[f*3+1], c2 = kw3[f*3+2], bb = bw3[f];
    #pragma unroll
    for (int q = 0; q < 4; q++){
      float z0 = relu_(fmaf(c0, yw[2*q],   fmaf(c1, yw[2*q+1], fmaf(c2, yw[2*q+2], bb))));
      float z1 = relu_(fmaf(c0, yw[2*q+1], fmaf(c1, yw[2*q+2], fmaf(c2, yw[2*q+3], bb))));
      flat_s[lane][q*3 + f] = fmaxf(z0, z1);
    }
  }
  {
    float c0 = km3[f*3], c1 = km3[f*3+1], c2 = km3[f*3+2], bb = bm3[f];
    #pragma unroll
    for (int q = 0; q < 4; q++){
      float z0 = relu_(fmaf(c0, ym[2*q],   fmaf(c1, ym[2*q+1], fmaf(c2, ym[2*q+2], bb))));
      float z1 = relu_(fmaf(c0, ym[2*q+1], fmaf(c1, ym[2*q+2], fmaf(c2, ym[2*q+3], bb))));
      flat_s[lane][12 + q*3 + f] = fmaxf(z0, z1);
    }
  }
  {
    float c0 = kn3[f*3], c1 = kn3[f*3+1], c2 = kn3[f*3+2], bb = bn3[f];
    #pragma unroll
    for (int q = 0; q < 4; q++){
      float z0 = relu_(fmaf(c0, yn[2*q],   fmaf(c1, yn[2*q+1], fmaf(c2, yn[2*q+2], bb))));
      float z1 = relu_(fmaf(c0, yn[2*q+1], fmaf(c1, yn[2*q+2], fmaf(c2, yn[2*q+3], bb))));
      flat_s[lane][24 + q*3 + f] = fmaxf(z0, z1);
    }
  }
  __syncthreads();

  // ---- fc1 ----
  #pragma unroll
  for (int oi = 0; oi < 6; oi++){
    const int o = 6*f + oi;
    float acc = fc1b[o];
    const float4* wrow = (const float4*)(fc1w + o*36);
    const float4* frow = (const float4*)(&flat_s[lane][0]);
    #pragma unroll
    for (int i = 0; i < 9; i++){
      float4 wv = wrow[i], fv = frow[i];
      acc = fmaf(wv.x, fv.x, acc); acc = fmaf(wv.y, fv.y, acc);
      acc = fmaf(wv.z, fv.z, acc); acc = fmaf(wv.w, fv.w, acc);
    }
    h1_s[lane][o] = relu_(acc);
  }
  __syncthreads();

  // ---- fc2 ----
  #pragma unroll
  for (int ei = 0; ei < 2; ei++){
    const int e = 2*f + ei;
    float acc = fc2b[e];
    #pragma unroll
    for (int o = 0; o < 18; o++) acc = fmaf(h1_s[lane][o], fc2w[e*18 + o], acc);
    seq[(n*SL + s)*ED + e] = relu_(acc);
  }
}

// ------------------------------ attention ----------------------------------
// grid 768 = 16 n * 3 h * 16 stiles ; 256 threads: 64 rows x 4 t-quarters.
__global__ __launch_bounds__(256) void attn_kernel(
  const float* __restrict__ seq, const float* __restrict__ inw,
  const float* __restrict__ inb, float* __restrict__ att_out, int layer)
{
  __shared__ float4 kv[1024];
  const int tid = threadIdx.x;
  const int bid = blockIdx.x;
  const int n = bid / 48;
  const int r = bid % 48;
  const int h = r >> 4;
  const int stile = r & 15;
  const float* W = inw + layer*108;
  const float* B = inb + layer*18;
  const int h2 = 2*h;
  const float* seqn = seq + n*SL*ED;
  const float SC = 1.0201265650432017f; // (1/sqrt(2)) * log2(e)

  float wk0[6], wk1[6], wv0[6], wv1[6];
  #pragma unroll
  for (int e = 0; e < 6; e++){
    wk0[e] = W[(6 + h2)*6 + e];  wk1[e] = W[(7 + h2)*6 + e];
    wv0[e] = W[(12 + h2)*6 + e]; wv1[e] = W[(13 + h2)*6 + e];
  }
  const float bk0 = B[6 + h2], bk1 = B[7 + h2], bv0 = B[12 + h2], bv1 = B[13 + h2];

  // kv[it*4 + q] holds t = q*256 + it  (so the 4 q-lanes read 4 consecutive
  // float4s -> 16 consecutive banks, conflict-free broadcast)
  for (int i = tid; i < 1024; i += 256){
    const int t = (i & 3)*256 + (i >> 2);
    const float* sr = seqn + t*6;
    float a0 = sr[0], a1 = sr[1], a2 = sr[2], a3 = sr[3], a4 = sr[4], a5 = sr[5];
    float k0 = bk0 + a0*wk0[0] + a1*wk0[1] + a2*wk0[2] + a3*wk0[3] + a4*wk0[4] + a5*wk0[5];
    float k1 = bk1 + a0*wk1[0] + a1*wk1[1] + a2*wk1[2] + a3*wk1[3] + a4*wk1[4] + a5*wk1[5];
    float v0 = bv0 + a0*wv0[0] + a1*wv0[1] + a2*wv0[2] + a3*wv0[3] + a4*wv0[4] + a5*wv0[5];
    float v1 = bv1 + a0*wv1[0] + a1*wv1[1] + a2*wv1[2] + a3*wv1[3] + a4*wv1[4] + a5*wv1[5];
    kv[i] = make_float4(k0*SC, k1*SC, v0, v1);
  }

  const int srow = stile*64 + (tid >> 2);
  const int q = tid & 3;
  float q0, q1;
  {
    const float* sr = seqn + srow*6;
    float a0 = sr[0], a1 = sr[1], a2 = sr[2], a3 = sr[3], a4 = sr[4], a5 = sr[5];
    q0 = B[h2]   + a0*W[h2*6]     + a1*W[h2*6+1]     + a2*W[h2*6+2]     + a3*W[h2*6+3]     + a4*W[h2*6+4]     + a5*W[h2*6+5];
    q1 = B[h2+1] + a0*W[(h2+1)*6] + a1*W[(h2+1)*6+1] + a2*W[(h2+1)*6+2] + a3*W[(h2+1)*6+3] + a4*W[(h2+1)*6+4] + a5*W[(h2+1)*6+5];
  }
  __syncthreads();

  float l = 0.f, o0 = 0.f, o1 = 0.f;
  #pragma unroll 8
  for (int it = 0; it < 256; it++){
    float4 K = kv[it*4 + q];
    float sc = fmaf(q0, K.x, q1*K.y);
    float p  = fexp2_(sc);
    l += p;
    o0 = fmaf(p, K.z, o0);
    o1 = fmaf(p, K.w, o1);
  }
  l  += __shfl_xor(l, 1);  l  += __shfl_xor(l, 2);
  o0 += __shfl_xor(o0, 1); o0 += __shfl_xor(o0, 2);
  o1 += __shfl_xor(o1, 1); o1 += __shfl_xor(o1, 2);
  if (q == 0){
    float inv = 1.0f / l;
    float* orow = att_out + (n*SL + srow)*ED + h2;
    orow[0] = o0*inv; orow[1] = o1*inv;
  }
}

// ------------------- fused oproj+LN1 + FF partial ---------------------------
// grid 512 = 128 token-tiles(128 tok) * 4 j-slices(512 rows); 256 threads.
// Weights staged in LDS (32 KB); lane = (tp: 8 tokens in regs, ss: row subset).
// Per ds_read of one row (4 x b128) -> 104 FMAs (8 tokens x 13).
__global__ __launch_bounds__(256) void ff_kernel(
  const float* __restrict__ seq_in, const float* __restrict__ att,
  const float* __restrict__ fcc,
  const float* __restrict__ ow, const float* __restrict__ ob,
  const float* __restrict__ l1w, const float* __restrict__ l1b,
  float* __restrict__ seq_mid, float* __restrict__ ffp, int layer)
{
  __shared__ float wc[512][16];  // 32 KB
  __shared__ float sM[128][6];
  const int tid   = threadIdx.x;
  const int tile  = blockIdx.x >> 2;
  const int slice = blockIdx.x & 3;
  const int tok0  = tile * 128;

  // stage weights
  const float4* FC = (const float4*)(fcc + (size_t)(layer*2048 + slice*512)*16);
  for (int i = tid; i < 2048; i += 256)
    ((float4*)wc)[i] = FC[i];

  // oproj + residual + LN1 for this tile's 128 tokens
  if (tid < 128){
    const int token = tok0 + tid;
    const float* a  = att + token*6;
    const float* W  = ow + layer*36;
    float av[6];
    #pragma unroll
    for (int e = 0; e < 6; e++) av[e] = a[e];
    float y[6]; float mu = 0.f;
    #pragma unroll
    for (int e = 0; e < 6; e++){
      float o = ob[layer*6 + e];
      #pragma unroll
      for (int e2 = 0; e2 < 6; e2++) o = fmaf(av[e2], W[e*6 + e2], o);
      y[e] = seq_in[token*6 + e] + o;
      mu += y[e];
    }
    mu *= (1.f/6.f);
    float var = 0.f;
    #pragma unroll
    for (int e = 0; e < 6; e++){ float d = y[e] - mu; var = fmaf(d, d, var); }
    var *= (1.f/6.f);
    float rstd = rsqrtf(var + 1e-5f);
    #pragma unroll
    for (int e = 0; e < 6; e++)
      sM[tid][e] = (y[e] - mu)*rstd*l1w[layer*6 + e] + l1b[layer*6 + e];
  }
  __syncthreads();

  const int w = tid >> 6, lane = tid & 63, tp = lane >> 2, ss = lane & 3;

  // 8 tokens in registers
  float sv[8][6];
  {
    const float* sp = &sM[tp*8][0];
    #pragma unroll
    for (int t = 0; t < 8; t++)
      #pragma unroll
      for (int e = 0; e < 6; e++) sv[t][e] = sp[t*6 + e];
  }
  float acc[8][6];
  #pragma unroll
  for (int t = 0; t < 8; t++)
    #pragma unroll
    for (int e = 0; e < 6; e++) acc[t][e] = 0.f;

  // rows w*128 + i*4 + ss  (ss-interleave -> 2-way bank alias, free)
  const int rb = w*128 + ss;
  #pragma unroll 2
  for (int i = 0; i < 32; i++){
    const float4* wr = (const float4*)&wc[rb + i*4][0];
    float4 w0 = wr[0], w1 = wr[1], w2 = wr[2], w3 = wr[3];
    #pragma unroll
    for (int t = 0; t < 8; t++){
      float h = w1.z;
      h = fmaf(sv[t][0], w0.x, h); h = fmaf(sv[t][1], w0.y, h);
      h = fmaf(sv[t][2], w0.z, h); h = fmaf(sv[t][3], w0.w, h);
      h = fmaf(sv[t][4], w1.x, h); h = fmaf(sv[t][5], w1.y, h);
      h = relu_(h);
      acc[t][0] = fmaf(h, w2.x, acc[t][0]); acc[t][1] = fmaf(h, w2.y, acc[t][1]);
      acc[t][2] = fmaf(h, w2.z, acc[t][2]); acc[t][3] = fmaf(h, w2.w, acc[t][3]);
      acc[t][4] = fmaf(h, w3.x, acc[t][4]); acc[t][5] = fmaf(h, w3.y, acc[t][5]);
    }
  }

  // reduce across ss
  #pragma unroll
  for (int t = 0; t < 8; t++)
    #pragma unroll
    for (int e = 0; e < 6; e++){
      acc[t][e] += __shfl_xor(acc[t][e], 1);
      acc[t][e] += __shfl_xor(acc[t][e], 2);
    }
  // cross-wave partial: waves own disjoint rows -> sum into ffp via per-slice,
  // per-wave entries?  No: waves also need summing.  Use LDS reduction.
  __syncthreads();  // reuse wc as scratch
  float* red = (float*)wc; // [4 waves][16 tp][48]
  if (ss == 0){
    #pragma unroll
    for (int t = 0; t < 8; t++)
      #pragma unroll
      for (int e = 0; e < 6; e++) red[(w*16 + tp)*48 + t*6 + e] = acc[t][e];
  }
  __syncthreads();
  // 128 tok * 6 e = 768 values; threads 0..255 each reduce 3 values over 4 waves
  for (int i = tid; i < 768; i += 256){
    const int tl = i / 6, e = i - tl*6;       // token-local 0..127
    const int rtp = tl >> 3, rt = tl & 7;
    float sum = red[(0*16 + rtp)*48 + rt*6 + e]
              + red[(1*16 + rtp)*48 + rt*6 + e]
              + red[(2*16 + rtp)*48 + rt*6 + e]
              + red[(3*16 + rtp)*48 + rt*6 + e];
    ffp[(size_t)(slice*16384 + tok0 + tl)*6 + e] = sum;
  }
  // one slice also publishes seq_mid for ffln
  if (slice == 0 && tid < 128){
    #pragma unroll
    for (int e = 0; e < 6; e++) seq_mid[(tok0 + tid)*6 + e] = sM[tid][e];
  }
}

// ---------------------------- FF-sum + LN2 ----------------------------------
__global__ __launch_bounds__(128) void ffln_kernel(
  const float* __restrict__ seq_mid, const float* __restrict__ ffp,
  const float* __restrict__ f2b, const float* __restrict__ lw,
  const float* __restrict__ lb, float* __restrict__ seq_out, int layer)
{
  const int tok = blockIdx.x*128 + threadIdx.x;
  float y[6]; float mu = 0.f;
  #pragma unroll
  for (int e = 0; e < 6; e++){
    float v = seq_mid[tok*6 + e] + f2b[layer*6 + e];
    v += ffp[(size_t)(0*16384 + tok)*6 + e];
    v += ffp[(size_t)(1*16384 + tok)*6 + e];
    v += ffp[(size_t)(2*16384 + tok)*6 + e];
    v += ffp[(size_t)(3*16384 + tok)*6 + e];
    y[e] = v; mu += v;
  }
  mu *= (1.f/6.f);
  float var = 0.f;
  #pragma unroll
  for (int e = 0; e < 6; e++){ float d = y[e] - mu; var = fmaf(d, d, var); }
  var *= (1.f/6.f);
  float rstd = rsqrtf(var + 1e-5f);
  #pragma unroll
  for (int e = 0; e < 6; e++)
    seq_out[tok*6 + e] = (y[e] - mu)*rstd*lw[layer*6 + e] + lb[layer*6 + e];
}

// ------------------------------- head ----------------------------------------
__global__ __launch_bounds__(192) void final_kernel(
  const float* __restrict__ seq, const float* __restrict__ o1w,
  const float* __restrict__ o1b, const float* __restrict__ o2w,
  float* __restrict__ out)
{
  __shared__ float red[6][33];
  __shared__ float pooled[6];
  const int n = blockIdx.x, tid = threadIdx.x, e = tid >> 5, ch = tid & 31;
  float s = 0.f;
  for (int i = ch; i < 1024; i += 32) s += seq[(n*SL + i)*ED + e];
  red[e][ch] = s;
  __syncthreads();
  if (tid < 6){
    float t = 0.f;
    for (int i = 0; i < 32; i++) t += red[tid][i];
    pooled[tid] = fmaxf(t * (1.f/1024.f), 0.f);
  }
  __syncthreads();
  if (tid == 0){
    float o1[7];
    #pragma unroll
    for (int o = 0; o < 7; o++){
      float a = o1b[o];
      #pragma unroll
      for (int e2 = 0; e2 < 6; e2++) a = fmaf(pooled[e2], o1w[o*6 + e2], a);
      o1[o] = relu_(a);
    }
    float lg[4];
    #pragma unroll
    for (int c = 0; c < 4; c++){
      float a = 0.f;
      #pragma unroll
      for (int o = 0; o < 7; o++) a = fmaf(o1[o], o2w[c*7 + o], a);
      lg[c] = a;
    }
    float m = fmaxf(fmaxf(lg[0], lg[1]), fmaxf(lg[2], lg[3]));
    float sum = 0.f;
    #pragma unroll
    for (int c = 0; c < 4; c++) sum += expf(lg[c] - m);
    float lse = m + logf(sum);
    #pragma unroll
    for (int c = 0; c < 4; c++) out[n*4 + c] = lg[c] - lse;
  }
}

// ------------------------------- launch --------------------------------------
extern "C" void kernel_launch(void* const* d_in, const int* in_sizes, int n_in,
                              void* d_out, int out_size, void* d_ws, size_t ws_size,
                              hipStream_t stream)
{
  const float* x    = (const float*)d_in[0];
  const float* k64  = (const float*)d_in[1];
  const float* b64  = (const float*)d_in[2];
  const float* k16  = (const float*)d_in[3];
  const float* b16  = (const float*)d_in[4];
  const float* k8   = (const float*)d_in[5];
  const float* b8   = (const float*)d_in[6];
  const float* kw3  = (const float*)d_in[7];
  const float* bw3  = (const float*)d_in[8];
  const float* km3  = (const float*)d_in[9];
  const float* bm3  = (const float*)d_in[10];
  const float* kn3  = (const float*)d_in[11];
  const float* bn3  = (const float*)d_in[12];
  const float* fc1w = (const float*)d_in[13];
  const float* fc1b = (const float*)d_in[14];
  const float* fc2w = (const float*)d_in[15];
  const float* fc2b = (const float*)d_in[16];
  const float* inw  = (const float*)d_in[17];
  const float* inb  = (const float*)d_in[18];
  const float* ow   = (const float*)d_in[19];
  const float* ob   = (const float*)d_in[20];
  const float* l1w  = (const float*)d_in[21];
  const float* l1b  = (const float*)d_in[22];
  const float* l2w  = (const float*)d_in[23];
  const float* l2b  = (const float*)d_in[24];
  const float* f1w  = (const float*)d_in[25];
  const float* f1b  = (const float*)d_in[26];
  const float* f2w  = (const float*)d_in[27];
  const float* f2b  = (const float*)d_in[28];
  const float* o1w  = (const float*)d_in[29];
  const float* o1b  = (const float*)d_in[30];
  const float* o2w  = (const float*)d_in[31];
  float* out = (float*)d_out;

  float* w = (float*)d_ws;
  float* seq_a   = w;                  // 98304
  float* seq_b   = w + 98304;          // 98304
  float* att     = w + 196608;         // 98304
  float* seq_mid = w + 294912;         // 98304
  float* ffp     = w + 393216;         // 393216
  float* fcc     = w + 786432;         // 65536
  // total 851968 floats ~= 3.3 MB

  frontend_kernel<<<256, 192, 0, stream>>>(x, k64, b64, k16, b16, k8, b8,
      kw3, bw3, km3, bm3, kn3, bn3, fc1w, fc1b, fc2w, fc2b,
      f1w, f1b, f2w, fcc, seq_a);
  attn_kernel<<<768, 256, 0, stream>>>(seq_a, inw, inb, att, 0);
  ff_kernel<<<512, 256, 0, stream>>>(seq_a, att, fcc, ow, ob, l1w, l1b,
      seq_mid, ffp, 0);
  ffln_kernel<<<128, 128, 0, stream>>>(seq_mid, ffp, f2b, l2w, l2b, seq_b, 0);
  attn_kernel<<<768, 256, 0, stream>>>(seq_b, inw, inb, att, 1);
  ff_kernel<<<512, 256, 0, stream>>>(seq_b, att, fcc, ow, ob, l1w, l1b,
      seq_mid, ffp, 1);
  ffln_kernel<<<128, 128, 0, stream>>>(seq_mid, ffp, f2b, l2w, l2b, seq_a, 1);
  final_kernel<<<16, 192, 0, stream>>>(seq_a, o1w, o1b, o2w, out);
}

// Round 4
// 82.364 us; speedup vs baseline: 2.2197x; 1.0784x over previous
//
#include <hip/hip_runtime.h>
#include <math.h>

// ---------------------------------------------------------------------------
// FluxAnomalyPredictionTF: F=3, E=6, H=3, d=2, FF=2048, N=16, T=2046, S=W=1024
// 7 dispatches: frontend(+fcc+qkv0) -> attn0 -> ff0 -> ffln0(+qkv1) ->
//               attn1 -> ff1 -> final(+ffln1)
// ---------------------------------------------------------------------------

#define NB 16
#define TL 2046
#define SL 1024
#define ED 6

__device__ __forceinline__ float relu_(float a){ return fmaxf(a, 0.f); }
__device__ __forceinline__ float fexp2_(float x){ return __builtin_amdgcn_exp2f(x); }

#define SCQK 1.0201265650432017f  // (1/sqrt(2)) * log2(e)

// ------------------------------ frontend -----------------------------------
// grid 256 = 16 n * 16 stiles ; 192 threads = 3 waves (wave = feature f)
// Also: builds fcc; computes layer-0 qkv -> kv4/qq.
__global__ __launch_bounds__(192) void frontend_kernel(
  const float* __restrict__ x, const float* __restrict__ k64,
  const float* __restrict__ b64, const float* __restrict__ k16, const float* __restrict__ b16,
  const float* __restrict__ k8,  const float* __restrict__ b8,
  const float* __restrict__ kw3, const float* __restrict__ bw3,
  const float* __restrict__ km3, const float* __restrict__ bm3,
  const float* __restrict__ kn3, const float* __restrict__ bn3,
  const float* __restrict__ fc1w, const float* __restrict__ fc1b,
  const float* __restrict__ fc2w, const float* __restrict__ fc2b,
  const float* __restrict__ f1w, const float* __restrict__ f1b,
  const float* __restrict__ f2w,
  const float* __restrict__ inw, const float* __restrict__ inb,
  float* __restrict__ fcc, float* __restrict__ seq,
  float4* __restrict__ kv4, float2* __restrict__ qq)
{
  __shared__ float xt[3][200];
  __shared__ float k64s[3*64*8];
  __shared__ float flat_s[64][44];
  __shared__ float h1_s[64][20];
  __shared__ float seq6[64][6];
  const int tid  = threadIdx.x;
  const int f    = tid >> 6;
  const int lane = tid & 63;
  const int n    = blockIdx.x >> 4;
  const int s0   = (blockIdx.x & 15) << 6;
  const int s    = s0 + lane;

  // ---- build fcc (global, for ff kernels) ----
  for (int i = blockIdx.x*192 + tid; i < 2*2048*16; i += 256*192){
    int l = i >> 15, r = i & 32767, j = r >> 4, c = r & 15;
    float v = 0.f;
    if (c < 6)       v = f1w[(l*2048 + j)*6 + c];
    else if (c == 6) v = f1b[l*2048 + j];
    else if (c >= 8 && c < 14) v = f2w[(l*6 + (c-8))*2048 + j];
    fcc[i] = v;
  }

  for (int i = tid; i < 600; i += 192){
    int ff = i / 200, pos = i - ff*200;
    int xp = 2*s0 - 39 + pos;
    xt[ff][pos] = (xp >= 0 && xp < TL) ? x[(n*TL + xp)*3 + ff] : 0.f;
  }
  for (int i = tid; i < 1536; i += 192){
    int ff = i >> 9, r = i & 511, t = r >> 3, k = r & 7;
    k64s[i] = k64[k*192 + ff*64 + t];
  }
  __syncthreads();

  float xr[74];
  {
    const int b = 2*lane;
    #pragma unroll
    for (int i = 0; i < 74; i++) xr[i] = xt[f][b + i];
  }

  // ---- wide: 64-tap ----
  float accw[8], acc_e0, acc_e1;
  #pragma unroll
  for (int k = 0; k < 8; k++) accw[k] = b64[k*3 + f];
  acc_e0 = accw[7]; acc_e1 = accw[0];
  {
    const float* kp = &k64s[f*512];
    #pragma unroll
    for (int t = 0; t < 64; t++){
      float4 wa = *(const float4*)(kp + t*8);
      float4 wb = *(const float4*)(kp + t*8 + 4);
      float xm = xr[8 + t];
      accw[0] = fmaf(xm, wa.x, accw[0]);
      accw[1] = fmaf(xm, wa.y, accw[1]);
      accw[2] = fmaf(xm, wa.z, accw[2]);
      accw[3] = fmaf(xm, wa.w, accw[3]);
      accw[4] = fmaf(xm, wb.x, accw[4]);
      accw[5] = fmaf(xm, wb.y, accw[5]);
      accw[6] = fmaf(xm, wb.z, accw[6]);
      accw[7] = fmaf(xm, wb.w, accw[7]);
      acc_e0 = fmaf(xr[6 + t],  wb.w, acc_e0);
      acc_e1 = fmaf(xr[10 + t], wa.x, acc_e1);
    }
  }
  float yw[10];
  yw[0] = (s > 0) ? 5.f*relu_(acc_e0) : 0.f;
  #pragma unroll
  for (int c = 1; c <= 8; c++) yw[c] = 5.f*relu_(accw[c-1]);
  yw[9] = (s < 1023) ? 5.f*relu_(acc_e1) : 0.f;

  // ---- mid: 16-tap ----
  float w16r[16];
  #pragma unroll
  for (int t = 0; t < 16; t++) w16r[t] = k16[f*16 + t];
  const float bb16 = b16[f];
  float ym[10];
  #pragma unroll
  for (int ci = 0; ci < 10; ci++){
    const int b = (ci == 0) ? 54 : ((ci == 9) ? 2 : 8*(ci-1));
    float a = bb16;
    #pragma unroll
    for (int t = 0; t < 16; t++) a = fmaf(xr[b + t], w16r[t], a);
    ym[ci] = relu_(a);
  }
  if (s == 0)    ym[0] = 0.f;
  if (s == 1023) ym[9] = 0.f;

  // ---- nar: 8-tap, max over 4 ----
  float w8r[8];
  #pragma unroll
  for (int t = 0; t < 8; t++) w8r[t] = k8[f*8 + t];
  const float bb8 = b8[f];
  float yn[10];
  #pragma unroll
  for (int ci = 0; ci < 10; ci++){
    float m = -3.0e38f;
    #pragma unroll
    for (int j2 = 0; j2 < 4; j2++){
      const int b = (ci == 0) ? (58 + 2*j2)
                  : ((ci == 9) ? (6 + 2*j2)
                               : (4 + 2*(4*(ci-1) + j2)));
      float a = bb8;
      #pragma unroll
      for (int t = 0; t < 8; t++) a = fmaf(xr[b + t], w8r[t], a);
      m = fmaxf(m, a);
    }
    yn[ci] = relu_(m);
  }
  if (s == 0)    yn[0] = 0.f;
  if (s == 1023) yn[9] = 0.f;

  // ---- conv3 + relu + pool2 -> flat ----
  {
    float c0 = kw3[f*3], c1 = kw3[f*3+1], c2 = kw3[f*3+2], bb = bw3[f];
    #pragma unroll
    for (int q = 0; q < 4; q++){
      float z0 = relu_(fmaf(c0, yw[2*q],   fmaf(c1, yw[2*q+1], fmaf(c2, yw[2*q+2], bb))));
      float z1 = relu_(fmaf(c0, yw[2*q+1], fmaf(c1, yw[2*q+2], fmaf(c2, yw[2*q+3], bb))));
      flat_s[lane][q*3 + f] = fmaxf(z0, z1);
    }
  }
  {
    float c0 = km3[f*3], c1 = km3[f*3+1], c2 = km3[f*3+2], bb = bm3[f];
    #pragma unroll
    for (int q = 0; q < 4; q++){
      float z0 = relu_(fmaf(c0, ym[2*q],   fmaf(c1, ym[2*q+1], fmaf(c2, ym[2*q+2], bb))));
      float z1 = relu_(fmaf(c0, ym[2*q+1], fmaf(c1, ym[2*q+2], fmaf(c2, ym[2*q+3], bb))));
      flat_s[lane][12 + q*3 + f] = fmaxf(z0, z1);
    }
  }
  {
    float c0 = kn3[f*3], c1 = kn3[f*3+1], c2 = kn3[f*3+2], bb = bn3[f];
    #pragma unroll
    for (int q = 0; q < 4; q++){
      float z0 = relu_(fmaf(c0, yn[2*q],   fmaf(c1, yn[2*q+1], fmaf(c2, yn[2*q+2], bb))));
      float z1 = relu_(fmaf(c0, yn[2*q+1], fmaf(c1, yn[2*q+2], fmaf(c2, yn[2*q+3], bb))));
      flat_s[lane][24 + q*3 + f] = fmaxf(z0, z1);
    }
  }
  __syncthreads();

  // ---- fc1 ----
  #pragma unroll
  for (int oi = 0; oi < 6; oi++){
    const int o = 6*f + oi;
    float acc = fc1b[o];
    const float4* wrow = (const float4*)(fc1w + o*36);
    const float4* frow = (const float4*)(&flat_s[lane][0]);
    #pragma unroll
    for (int i = 0; i < 9; i++){
      float4 wv = wrow[i], fv = frow[i];
      acc = fmaf(wv.x, fv.x, acc); acc = fmaf(wv.y, fv.y, acc);
      acc = fmaf(wv.z, fv.z, acc); acc = fmaf(wv.w, fv.w, acc);
    }
    h1_s[lane][o] = relu_(acc);
  }
  __syncthreads();

  // ---- fc2 ----
  #pragma unroll
  for (int ei = 0; ei < 2; ei++){
    const int e = 2*f + ei;
    float acc = fc2b[e];
    #pragma unroll
    for (int o = 0; o < 18; o++) acc = fmaf(h1_s[lane][o], fc2w[e*18 + o], acc);
    seq[(n*SL + s)*ED + e] = acc < 0.f ? 0.f : acc;
    seq6[lane][e] = acc < 0.f ? 0.f : acc;
  }
  __syncthreads();

  // ---- layer-0 qkv: thread = (head g = f, token = lane) ----
  {
    const int g = f;
    float sv[6];
    #pragma unroll
    for (int e = 0; e < 6; e++) sv[e] = seq6[lane][e];
    const float* W = inw;     // layer 0
    const float* B = inb;
    const int h2 = 2*g;
    float q0 = B[h2],   q1 = B[h2+1];
    float k0 = B[6+h2], k1 = B[7+h2];
    float v0 = B[12+h2], v1 = B[13+h2];
    #pragma unroll
    for (int e = 0; e < 6; e++){
      q0 = fmaf(sv[e], W[h2*6 + e],      q0);
      q1 = fmaf(sv[e], W[(h2+1)*6 + e],  q1);
      k0 = fmaf(sv[e], W[(6+h2)*6 + e],  k0);
      k1 = fmaf(sv[e], W[(7+h2)*6 + e],  k1);
      v0 = fmaf(sv[e], W[(12+h2)*6 + e], v0);
      v1 = fmaf(sv[e], W[(13+h2)*6 + e], v1);
    }
    const int nh = n*3 + g;
    kv4[nh*SL + s] = make_float4(k0*SCQK, k1*SCQK, v0, v1);
    qq [nh*SL + s] = make_float2(q0, q1);
  }
}

// ------------------------------ attention ----------------------------------
// grid (16 rb, 3 h, 16 n); 256 thr = 4 waves. Wave owns 16 q-rows; lanes span
// t: each ds_read_b128 (distinct t per lane) feeds 16 rows x 5 VALU.
// q0/q1 are wave-uniform -> SGPR. 3-level shfl reduce + LDS phase2.
__global__ __launch_bounds__(256) void attn_kernel(
  const float4* __restrict__ kv4, const float2* __restrict__ qq,
  float* __restrict__ att_out)
{
  __shared__ float4 sKV[1024];
  __shared__ float red[4][8][16][3];
  const int tid  = threadIdx.x;
  const int w    = tid >> 6;
  const int lane = tid & 63;
  const int rb   = blockIdx.x << 6;
  const int h    = blockIdx.y;
  const int n    = blockIdx.z;
  const int nh   = n*3 + h;

  const float4* kvp = kv4 + nh*SL;
  #pragma unroll
  for (int i = 0; i < 4; i++) sKV[tid + i*256] = kvp[tid + i*256];

  // 16 rows' q (wave-uniform -> scalar loads)
  const int r0 = rb + w*16;
  float q0[16], q1[16];
  {
    const float2* qp = qq + nh*SL + r0;
    #pragma unroll
    for (int r = 0; r < 16; r++){ float2 qv = qp[r]; q0[r] = qv.x; q1[r] = qv.y; }
  }
  __syncthreads();

  float l[16], o0[16], o1[16];
  #pragma unroll
  for (int r = 0; r < 16; r++){ l[r] = 0.f; o0[r] = 0.f; o1[r] = 0.f; }

  #pragma unroll 2
  for (int i = 0; i < 16; i++){
    float4 K = sKV[i*64 + lane];
    #pragma unroll
    for (int r = 0; r < 16; r++){
      float sc = fmaf(q0[r], K.x, q1[r]*K.y);
      float p  = fexp2_(sc);
      l[r] += p;
      o0[r] = fmaf(p, K.z, o0[r]);
      o1[r] = fmaf(p, K.w, o1[r]);
    }
  }

  // reduce within 8-lane groups
  #pragma unroll
  for (int r = 0; r < 16; r++){
    l[r]  += __shfl_xor(l[r], 1);  l[r]  += __shfl_xor(l[r], 2);  l[r]  += __shfl_xor(l[r], 4);
    o0[r] += __shfl_xor(o0[r], 1); o0[r] += __shfl_xor(o0[r], 2); o0[r] += __shfl_xor(o0[r], 4);
    o1[r] += __shfl_xor(o1[r], 1); o1[r] += __shfl_xor(o1[r], 2); o1[r] += __shfl_xor(o1[r], 4);
  }
  {
    const int g = lane >> 3;
    #pragma unroll
    for (int r = 0; r < 16; r++){
      if ((lane & 7) == (r & 7)){   // static reg index, predicated store
        red[w][g][r][0] = l[r];
        red[w][g][r][1] = o0[r];
        red[w][g][r][2] = o1[r];
      }
    }
  }
  __syncthreads();

  if (tid < 64){
    const int ww = tid >> 4, r = tid & 15;
    float L = 0.f, O0 = 0.f, O1 = 0.f;
    #pragma unroll
    for (int g = 0; g < 8; g++){
      L  += red[ww][g][r][0];
      O0 += red[ww][g][r][1];
      O1 += red[ww][g][r][2];
    }
    const int row = rb + ww*16 + r;
    const float inv = 1.0f / L;
    float* orow = att_out + (n*SL + row)*ED + 2*h;
    orow[0] = O0*inv; orow[1] = O1*inv;
  }
}

// ------------------- fused oproj+LN1 + FF partial ---------------------------
// grid 512 = 128 token-tiles(128 tok) * 4 j-slices(512 rows); 256 threads.
__global__ __launch_bounds__(256) void ff_kernel(
  const float* __restrict__ seq_in, const float* __restrict__ att,
  const float* __restrict__ fcc,
  const float* __restrict__ ow, const float* __restrict__ ob,
  const float* __restrict__ l1w, const float* __restrict__ l1b,
  float* __restrict__ seq_mid, float* __restrict__ ffp, int layer)
{
  __shared__ float wc[512][16];  // 32 KB
  __shared__ float sM[128][6];
  const int tid   = threadIdx.x;
  const int tile  = blockIdx.x >> 2;
  const int slice = blockIdx.x & 3;
  const int tok0  = tile * 128;

  const float4* FC = (const float4*)(fcc + (size_t)(layer*2048 + slice*512)*16);
  for (int i = tid; i < 2048; i += 256)
    ((float4*)wc)[i] = FC[i];

  if (tid < 128){
    const int token = tok0 + tid;
    const float* a  = att + token*6;
    const float* W  = ow + layer*36;
    float av[6];
    #pragma unroll
    for (int e = 0; e < 6; e++) av[e] = a[e];
    float y[6]; float mu = 0.f;
    #pragma unroll
    for (int e = 0; e < 6; e++){
      float o = ob[layer*6 + e];
      #pragma unroll
      for (int e2 = 0; e2 < 6; e2++) o = fmaf(av[e2], W[e*6 + e2], o);
      y[e] = seq_in[token*6 + e] + o;
      mu += y[e];
    }
    mu *= (1.f/6.f);
    float var = 0.f;
    #pragma unroll
    for (int e = 0; e < 6; e++){ float d = y[e] - mu; var = fmaf(d, d, var); }
    var *= (1.f/6.f);
    float rstd = rsqrtf(var + 1e-5f);
    #pragma unroll
    for (int e = 0; e < 6; e++)
      sM[tid][e] = (y[e] - mu)*rstd*l1w[layer*6 + e] + l1b[layer*6 + e];
  }
  __syncthreads();

  const int w = tid >> 6, lane = tid & 63, tp = lane >> 2, ss = lane & 3;

  float sv[8][6];
  {
    const float* sp = &sM[tp*8][0];
    #pragma unroll
    for (int t = 0; t < 8; t++)
      #pragma unroll
      for (int e = 0; e < 6; e++) sv[t][e] = sp[t*6 + e];
  }
  float acc[8][6];
  #pragma unroll
  for (int t = 0; t < 8; t++)
    #pragma unroll
    for (int e = 0; e < 6; e++) acc[t][e] = 0.f;

  const int rb = w*128 + ss;
  #pragma unroll 2
  for (int i = 0; i < 32; i++){
    const float4* wr = (const float4*)&wc[rb + i*4][0];
    float4 w0 = wr[0], w1 = wr[1], w2 = wr[2], w3 = wr[3];
    #pragma unroll
    for (int t = 0; t < 8; t++){
      float h = w1.z;
      h = fmaf(sv[t][0], w0.x, h); h = fmaf(sv[t][1], w0.y, h);
      h = fmaf(sv[t][2], w0.z, h); h = fmaf(sv[t][3], w0.w, h);
      h = fmaf(sv[t][4], w1.x, h); h = fmaf(sv[t][5], w1.y, h);
      h = relu_(h);
      acc[t][0] = fmaf(h, w2.x, acc[t][0]); acc[t][1] = fmaf(h, w2.y, acc[t][1]);
      acc[t][2] = fmaf(h, w2.z, acc[t][2]); acc[t][3] = fmaf(h, w2.w, acc[t][3]);
      acc[t][4] = fmaf(h, w3.x, acc[t][4]); acc[t][5] = fmaf(h, w3.y, acc[t][5]);
    }
  }

  #pragma unroll
  for (int t = 0; t < 8; t++)
    #pragma unroll
    for (int e = 0; e < 6; e++){
      acc[t][e] += __shfl_xor(acc[t][e], 1);
      acc[t][e] += __shfl_xor(acc[t][e], 2);
    }
  __syncthreads();   // reuse wc as reduction scratch
  float* red = (float*)wc; // [4 waves][16 tp][48]
  if (ss == 0){
    #pragma unroll
    for (int t = 0; t < 8; t++)
      #pragma unroll
      for (int e = 0; e < 6; e++) red[(w*16 + tp)*48 + t*6 + e] = acc[t][e];
  }
  __syncthreads();
  for (int i = tid; i < 768; i += 256){
    const int tl = i / 6, e = i - tl*6;
    const int rtp = tl >> 3, rt = tl & 7;
    float sum = red[(0*16 + rtp)*48 + rt*6 + e]
              + red[(1*16 + rtp)*48 + rt*6 + e]
              + red[(2*16 + rtp)*48 + rt*6 + e]
              + red[(3*16 + rtp)*48 + rt*6 + e];
    ffp[(size_t)(slice*16384 + tok0 + tl)*6 + e] = sum;
  }
  if (slice == 0 && tid < 128){
    #pragma unroll
    for (int e = 0; e < 6; e++) seq_mid[(tok0 + tid)*6 + e] = sM[tid][e];
  }
}

// ------------------- FF-sum + LN2 + next-layer qkv --------------------------
// layer-0 epilogue: writes seq_out and kv4/qq for layer 1.
__global__ __launch_bounds__(128) void ffln_kernel(
  const float* __restrict__ seq_mid, const float* __restrict__ ffp,
  const float* __restrict__ f2b, const float* __restrict__ lw,
  const float* __restrict__ lb,
  const float* __restrict__ Wq, const float* __restrict__ Bq,
  float* __restrict__ seq_out, float4* __restrict__ kv4, float2* __restrict__ qq)
{
  const int tok = blockIdx.x*128 + threadIdx.x;
  float y[6]; float mu = 0.f;
  #pragma unroll
  for (int e = 0; e < 6; e++){
    float v = seq_mid[tok*6 + e] + f2b[e];
    v += ffp[(size_t)(0*16384 + tok)*6 + e];
    v += ffp[(size_t)(1*16384 + tok)*6 + e];
    v += ffp[(size_t)(2*16384 + tok)*6 + e];
    v += ffp[(size_t)(3*16384 + tok)*6 + e];
    y[e] = v; mu += v;
  }
  mu *= (1.f/6.f);
  float var = 0.f;
  #pragma unroll
  for (int e = 0; e < 6; e++){ float d = y[e] - mu; var = fmaf(d, d, var); }
  var *= (1.f/6.f);
  float rstd = rsqrtf(var + 1e-5f);
  float sv[6];
  #pragma unroll
  for (int e = 0; e < 6; e++){
    sv[e] = (y[e] - mu)*rstd*lw[e] + lb[e];
    seq_out[tok*6 + e] = sv[e];
  }

  const int n = tok >> 10, t = tok & 1023;
  #pragma unroll
  for (int g = 0; g < 3; g++){
    const int h2 = 2*g;
    float q0 = Bq[h2],   q1 = Bq[h2+1];
    float k0 = Bq[6+h2], k1 = Bq[7+h2];
    float v0 = Bq[12+h2], v1 = Bq[13+h2];
    #pragma unroll
    for (int e = 0; e < 6; e++){
      q0 = fmaf(sv[e], Wq[h2*6 + e],      q0);
      q1 = fmaf(sv[e], Wq[(h2+1)*6 + e],  q1);
      k0 = fmaf(sv[e], Wq[(6+h2)*6 + e],  k0);
      k1 = fmaf(sv[e], Wq[(7+h2)*6 + e],  k1);
      v0 = fmaf(sv[e], Wq[(12+h2)*6 + e], v0);
      v1 = fmaf(sv[e], Wq[(13+h2)*6 + e], v1);
    }
    const int nh = n*3 + g;
    kv4[nh*SL + t] = make_float4(k0*SCQK, k1*SCQK, v0, v1);
    qq [nh*SL + t] = make_float2(q0, q1);
  }
}

// --------------------- head (+ layer-1 FF-sum + LN2) -------------------------
// 16 blocks (one per n) x 256 thr; each thread finishes 4 tokens' LN2 and
// accumulates the mean; then wave+block reduce, classifier head, log_softmax.
__global__ __launch_bounds__(256) void final_kernel(
  const float* __restrict__ seq_mid, const float* __restrict__ ffp,
  const float* __restrict__ f2b, const float* __restrict__ lw,
  const float* __restrict__ lb,
  const float* __restrict__ o1w, const float* __restrict__ o1b,
  const float* __restrict__ o2w, float* __restrict__ out)
{
  __shared__ float fred[4][6];
  __shared__ float pooled[6];
  const int n = blockIdx.x, tid = threadIdx.x;
  float psum[6] = {0,0,0,0,0,0};

  #pragma unroll
  for (int i = 0; i < 4; i++){
    const int tok = n*SL + tid + i*256;
    float y[6]; float mu = 0.f;
    #pragma unroll
    for (int e = 0; e < 6; e++){
      float v = seq_mid[tok*6 + e] + f2b[e];
      v += ffp[(size_t)(0*16384 + tok)*6 + e];
      v += ffp[(size_t)(1*16384 + tok)*6 + e];
      v += ffp[(size_t)(2*16384 + tok)*6 + e];
      v += ffp[(size_t)(3*16384 + tok)*6 + e];
      y[e] = v; mu += v;
    }
    mu *= (1.f/6.f);
    float var = 0.f;
    #pragma unroll
    for (int e = 0; e < 6; e++){ float d = y[e] - mu; var = fmaf(d, d, var); }
    var *= (1.f/6.f);
    float rstd = rsqrtf(var + 1e-5f);
    #pragma unroll
    for (int e = 0; e < 6; e++)
      psum[e] += (y[e] - mu)*rstd*lw[e] + lb[e];
  }

  // full-wave reduce of psum
  #pragma unroll
  for (int e = 0; e < 6; e++){
    psum[e] += __shfl_xor(psum[e], 1);  psum[e] += __shfl_xor(psum[e], 2);
    psum[e] += __shfl_xor(psum[e], 4);  psum[e] += __shfl_xor(psum[e], 8);
    psum[e] += __shfl_xor(psum[e], 16); psum[e] += __shfl_xor(psum[e], 32);
  }
  if ((tid & 63) == 0){
    #pragma unroll
    for (int e = 0; e < 6; e++) fred[tid >> 6][e] = psum[e];
  }
  __syncthreads();
  if (tid < 6){
    float t = fred[0][tid] + fred[1][tid] + fred[2][tid] + fred[3][tid];
    pooled[tid] = fmaxf(t * (1.f/1024.f), 0.f);
  }
  __syncthreads();
  if (tid == 0){
    float o1[7];
    #pragma unroll
    for (int o = 0; o < 7; o++){
      float a = o1b[o];
      #pragma unroll
      for (int e2 = 0; e2 < 6; e2++) a = fmaf(pooled[e2], o1w[o*6 + e2], a);
      o1[o] = relu_(a);
    }
    float lg[4];
    #pragma unroll
    for (int c = 0; c < 4; c++){
      float a = 0.f;
      #pragma unroll
      for (int o = 0; o < 7; o++) a = fmaf(o1[o], o2w[c*7 + o], a);
      lg[c] = a;
    }
    float m = fmaxf(fmaxf(lg[0], lg[1]), fmaxf(lg[2], lg[3]));
    float sum = 0.f;
    #pragma unroll
    for (int c = 0; c < 4; c++) sum += expf(lg[c] - m);
    float lse = m + logf(sum);
    #pragma unroll
    for (int c = 0; c < 4; c++) out[n*4 + c] = lg[c] - lse;
  }
}

// ------------------------------- launch --------------------------------------
extern "C" void kernel_launch(void* const* d_in, const int* in_sizes, int n_in,
                              void* d_out, int out_size, void* d_ws, size_t ws_size,
                              hipStream_t stream)
{
  const float* x    = (const float*)d_in[0];
  const float* k64  = (const float*)d_in[1];
  const float* b64  = (const float*)d_in[2];
  const float* k16  = (const float*)d_in[3];
  const float* b16  = (const float*)d_in[4];
  const float* k8   = (const float*)d_in[5];
  const float* b8   = (const float*)d_in[6];
  const float* kw3  = (const float*)d_in[7];
  const float* bw3  = (const float*)d_in[8];
  const float* km3  = (const float*)d_in[9];
  const float* bm3  = (const float*)d_in[10];
  const float* kn3  = (const float*)d_in[11];
  const float* bn3  = (const float*)d_in[12];
  const float* fc1w = (const float*)d_in[13];
  const float* fc1b = (const float*)d_in[14];
  const float* fc2w = (const float*)d_in[15];
  const float* fc2b = (const float*)d_in[16];
  const float* inw  = (const float*)d_in[17];
  const float* inb  = (const float*)d_in[18];
  const float* ow   = (const float*)d_in[19];
  const float* ob   = (const float*)d_in[20];
  const float* l1w  = (const float*)d_in[21];
  const float* l1b  = (const float*)d_in[22];
  const float* l2w  = (const float*)d_in[23];
  const float* l2b  = (const float*)d_in[24];
  const float* f1w  = (const float*)d_in[25];
  const float* f1b  = (const float*)d_in[26];
  const float* f2w  = (const float*)d_in[27];
  const float* f2b  = (const float*)d_in[28];
  const float* o1w  = (const float*)d_in[29];
  const float* o1b  = (const float*)d_in[30];
  const float* o2w  = (const float*)d_in[31];
  float* out = (float*)d_out;

  float* w = (float*)d_ws;
  float*  seq_a   = w;                       // 98304
  float*  seq_b   = w + 98304;               // 98304
  float*  att     = w + 196608;              // 98304
  float*  seq_mid = w + 294912;              // 98304
  float*  ffp     = w + 393216;              // 393216
  float*  fcc     = w + 786432;              // 65536
  float4* kv4     = (float4*)(w + 851968);   // 49152 float4 = 196608 floats
  float2* qq      = (float2*)(w + 1048576);  // 49152 float2 = 98304 floats
  // total 1146880 floats ~= 4.6 MB

  frontend_kernel<<<256, 192, 0, stream>>>(x, k64, b64, k16, b16, k8, b8,
      kw3, bw3, km3, bm3, kn3, bn3, fc1w, fc1b, fc2w, fc2b,
      f1w, f1b, f2w, inw, inb, fcc, seq_a, kv4, qq);

  dim3 agrid(16, 3, 16);
  attn_kernel<<<agrid, 256, 0, stream>>>(kv4, qq, att);
  ff_kernel<<<512, 256, 0, stream>>>(seq_a, att, fcc, ow, ob, l1w, l1b,
      seq_mid, ffp, 0);
  ffln_kernel<<<128, 128, 0, stream>>>(seq_mid, ffp, f2b, l2w, l2b,
      inw + 108, inb + 18, seq_b, kv4, qq);

  attn_kernel<<<agrid, 256, 0, stream>>>(kv4, qq, att);
  ff_kernel<<<512, 256, 0, stream>>>(seq_b, att, fcc, ow, ob, l1w, l1b,
      seq_mid, ffp, 1);
  final_kernel<<<16, 256, 0, stream>>>(seq_mid, ffp, f2b + 6, l2w + 6, l2b + 6,
      o1w, o1b, o2w, out);
}